// Round 2
// baseline (312.697 us; speedup 1.0000x reference)
//
#include <hip/hip_runtime.h>
#include <hip/hip_bf16.h>

typedef __attribute__((ext_vector_type(8))) short bf16x8;
typedef __attribute__((ext_vector_type(4))) float f32x4;

#define CSTRIDE 9216   // coeff row stride = O*(D+1)
#define KT2 8192       // GEMM K: polys T_1..T_8, k = (d-1)*1024 + i
#define NOUT 1024

static __device__ __forceinline__ unsigned short f2bf(float f) {
    union { __hip_bfloat16 h; unsigned short u; } cv;
    cv.h = __float2bfloat16(f);
    return cv.u;
}
static __device__ __forceinline__ float bf2f(unsigned short u) {
    union { float f; unsigned v; } c; c.v = (unsigned)u << 16; return c.f;
}
static __device__ __forceinline__ float fast_tanhf(float v) {
    float e = __expf(2.0f * v);
    return 1.0f - 2.0f / (e + 1.0f);
}

// ---------------------------------------------------------------------------
// Prep: cc (I=1024, O=1024, 9) f32 -> Wt[n][k] bf16 (k=(d-1)*1024+i, d=1..8,
// row stride 8192, linear — B is consumed global->reg now, no swizzle), plus
// bias[o] = sum_i cc[i][o][0] via fp32 atomics (T_0 contribution).
// ---------------------------------------------------------------------------
__global__ void __launch_bounds__(256) prep_kernel(const float* __restrict__ cc,
                                                   unsigned short* __restrict__ Wt,
                                                   float* __restrict__ bias) {
    __shared__ unsigned short T[288 * 68];  // [f = nl*9 + d][il], pad 68
    const int t  = threadIdx.x;
    const int n0 = (blockIdx.x & 31) * 32;
    const int i0 = (blockIdx.x >> 5) * 64;

    for (int il = 0; il < 64; ++il) {
        const float* src = cc + (size_t)(i0 + il) * CSTRIDE + (size_t)n0 * 9;
        for (int f = t; f < 288; f += 256)
            T[f * 68 + il] = f2bf(src[f]);
    }
    __syncthreads();

    // 256 chunks (nl 0..31, d 1..8); each chunk = 64 contiguous elems out.
#pragma unroll
    for (int it = 0; it < 16; ++it) {
        const int chunk = it * 16 + (t >> 4);
        const int nl = chunk >> 3;
        const int d  = (chunk & 7) + 1;
        const int e0 = (t & 15) * 4;
        ushort4 v = *(const ushort4*)&T[(nl * 9 + d) * 68 + e0];
        *(ushort4*)(Wt + (size_t)(n0 + nl) * KT2 + (d - 1) * 1024 + i0 + e0) = v;
    }

    if (t < 32) {
        float s = 0.f;
#pragma unroll 8
        for (int il = 0; il < 64; ++il) s += bf2f(T[(t * 9) * 68 + il]);
        atomicAdd(&bias[n0 + t], s);
    }
}

// ---------------------------------------------------------------------------
// Fused GEMM: out[8192][1024] = Cheby_{1..8}(tanh(x)) @ Wt^T + bias
// BM=64 x BN=256 tile, 256 threads = 4 waves (each 64 rows x 64 cols).
// A generated in-register (fp32 recurrence), ds_written XOR-swizzled,
// DOUBLE-BUFFERED (gen s+1 overlaps MFMA s) -> 1 barrier/step.
// B fragments: direct global->reg loads from L2-resident panel, register-
// prefetched one step ahead and left in flight across the raw s_barrier.
// ---------------------------------------------------------------------------
__global__ void __launch_bounds__(256, 2)
cheby_gemm(const float* __restrict__ x, const unsigned short* __restrict__ Wt,
           const float* __restrict__ bias, float* __restrict__ out) {
    __shared__ unsigned short Asub[2][64 * 64];  // 2 x 8 KB, [row][kc] swizzled

    const int id   = blockIdx.x;       // 512 blocks
    const int bcol = (id & 3) * 256;   // col strip: fixed per XCD (id&7 -> xcd)
    const int brow = (id >> 2) * 64;
    const int t    = threadIdx.x;
    const int lane = t & 63;
    const int w    = t >> 6;
    const int wc   = w * 64;           // wave's col offset; all waves share rows
    const int l15  = lane & 15;
    const int lhi  = lane >> 4;

    // generation mapping: thread covers rows rr+16p (p=0..3), i-quad gi0..+3
    const int gi0 = (t & 15) * 4;
    const int rr  = t >> 4;            // 0..15

    unsigned awoff[4];
#pragma unroll
    for (int p = 0; p < 4; ++p) {
        const int r = rr + 16 * p;
        awoff[p] = r * 128 + ((gi0 * 2) ^ ((r & 7) << 4));
    }

    f32x4 acc[4][4] = {};
    float x2[4][4], Tp[4][4], Tpp[4][4];
    bf16x8 bcur[2][4];

    const unsigned short* wbase = Wt + (size_t)(bcol + wc) * KT2 + lhi * 8;

    // ---- prologue: T1 for ic=0 into Asub[0]; prefetch B for step 0 ----
#pragma unroll
    for (int p = 0; p < 4; ++p) {
        const float4 v = *(const float4*)(x + (size_t)(brow + rr + 16 * p) * 1024 + gi0);
        ushort4 pk; unsigned short* pks = (unsigned short*)&pk;
#pragma unroll
        for (int j = 0; j < 4; ++j) {
            const float xv = (&v.x)[j];
            x2[p][j] = 2.0f * fast_tanhf(xv);
            const float c = 0.5f * x2[p][j];
            Tp[p][j] = c; Tpp[p][j] = 1.0f;
            pks[j] = f2bf(c);
        }
        *(ushort4*)((char*)Asub[0] + awoff[p]) = pk;
    }
#pragma unroll
    for (int ks = 0; ks < 2; ++ks)
#pragma unroll
        for (int nf = 0; nf < 4; ++nf)
            bcur[ks][nf] = *(const bf16x8*)(wbase + (size_t)(nf * 16 + l15) * KT2 + ks * 32);
    asm volatile("s_waitcnt lgkmcnt(0)" ::: "memory");
    __builtin_amdgcn_s_barrier();

#pragma unroll 1
    for (int ic = 0; ic < 16; ++ic) {
#pragma unroll
        for (int dd = 0; dd < 8; ++dd) {
            const int cur = dd & 1;
            const int nxt = cur ^ 1;
            // next step coords (wraps harmlessly at the very end)
            const int ddn = (dd + 1) & 7;
            const int icn = (dd == 7) ? ((ic + 1) & 15) : ic;
            const int kbn = ddn * 1024 + icn * 64;

            // (1) prefetch B fragments for step s+1 (left in flight over barrier)
            bf16x8 bnxt[2][4];
#pragma unroll
            for (int ks = 0; ks < 2; ++ks)
#pragma unroll
                for (int nf = 0; nf < 4; ++nf)
                    bnxt[ks][nf] = *(const bf16x8*)(wbase + (size_t)(nf * 16 + l15) * KT2
                                                    + kbn + ks * 32);

            // (2) A fragment reads for this step
            bf16x8 af[2][4];
#pragma unroll
            for (int ks = 0; ks < 2; ++ks)
#pragma unroll
                for (int mf = 0; mf < 4; ++mf) {
                    const int row = mf * 16 + l15;
                    af[ks][mf] = *(const bf16x8*)((const char*)Asub[cur] + row * 128 +
                                  ((ks * 64 + lhi * 16) ^ ((row & 7) << 4)));
                }

            // (3) generate next step's A tile into the other buffer
            if (dd == 7) {
#pragma unroll
                for (int p = 0; p < 4; ++p) {
                    const float4 v = *(const float4*)(x + (size_t)(brow + rr + 16 * p) * 1024
                                                      + icn * 64 + gi0);
                    ushort4 pk; unsigned short* pks = (unsigned short*)&pk;
#pragma unroll
                    for (int j = 0; j < 4; ++j) {
                        const float xv = (&v.x)[j];
                        x2[p][j] = 2.0f * fast_tanhf(xv);
                        const float c = 0.5f * x2[p][j];
                        Tp[p][j] = c; Tpp[p][j] = 1.0f;
                        pks[j] = f2bf(c);
                    }
                    *(ushort4*)((char*)Asub[nxt] + awoff[p]) = pk;
                }
            } else {
#pragma unroll
                for (int p = 0; p < 4; ++p) {
                    ushort4 pk; unsigned short* pks = (unsigned short*)&pk;
#pragma unroll
                    for (int j = 0; j < 4; ++j) {
                        const float c = __builtin_fmaf(x2[p][j], Tp[p][j], -Tpp[p][j]);
                        Tpp[p][j] = Tp[p][j]; Tp[p][j] = c;
                        pks[j] = f2bf(c);
                    }
                    *(ushort4*)((char*)Asub[nxt] + awoff[p]) = pk;
                }
            }

            // (4) MFMA on current buffers
#pragma unroll
            for (int ks = 0; ks < 2; ++ks)
#pragma unroll
                for (int mf = 0; mf < 4; ++mf)
#pragma unroll
                    for (int nf = 0; nf < 4; ++nf)
                        acc[mf][nf] = __builtin_amdgcn_mfma_f32_16x16x32_bf16(
                            af[ks][mf], bcur[ks][nf], acc[mf][nf], 0, 0, 0);

            // (5) A writes visible, then barrier — vmcnt NOT drained
            asm volatile("s_waitcnt lgkmcnt(0)" ::: "memory");
            __builtin_amdgcn_s_barrier();

#pragma unroll
            for (int ks = 0; ks < 2; ++ks)
#pragma unroll
                for (int nf = 0; nf < 4; ++nf)
                    bcur[ks][nf] = bnxt[ks][nf];
        }
    }

    // epilogue: C/D layout col = lane&15, row = (lane>>4)*4 + reg; add bias
    float bv[4];
#pragma unroll
    for (int nf = 0; nf < 4; ++nf) bv[nf] = bias[bcol + wc + nf * 16 + l15];
#pragma unroll
    for (int mf = 0; mf < 4; ++mf)
#pragma unroll
        for (int nf = 0; nf < 4; ++nf)
#pragma unroll
            for (int ri = 0; ri < 4; ++ri) {
                const int orow = brow + mf * 16 + lhi * 4 + ri;
                const int ocol = bcol + wc + nf * 16 + l15;
                out[(size_t)orow * NOUT + ocol] = acc[mf][nf][ri] + bv[nf];
            }
}

// ---------------------------------------------------------------------------
// Fallback (only if ws too small): correct but slow fp32 path.
// ---------------------------------------------------------------------------
__global__ void __launch_bounds__(256) naive_kernel(const float* __restrict__ x,
                                                    const float* __restrict__ cc,
                                                    float* __restrict__ out) {
    __shared__ float xs[1024];
    const int b = blockIdx.x;
    const int t = threadIdx.x;
#pragma unroll
    for (int j = 0; j < 4; ++j)
        xs[t * 4 + j] = fast_tanhf(x[(size_t)b * 1024 + t * 4 + j]);
    __syncthreads();

    const int o = t * 4;
    float a0 = 0.f, a1 = 0.f, a2 = 0.f, a3 = 0.f;
    for (int i = 0; i < 1024; ++i) {
        const float* cp = cc + (size_t)i * CSTRIDE + (size_t)o * 9;
        const float xv = xs[i];
        float tpp = 1.0f, tp = xv;
        a0 += cp[0];  a1 += cp[9];  a2 += cp[18];  a3 += cp[27];
        a0 += xv * cp[1]; a1 += xv * cp[10]; a2 += xv * cp[19]; a3 += xv * cp[28];
#pragma unroll
        for (int d = 2; d <= 8; ++d) {
            const float cur = 2.0f * xv * tp - tpp;
            tpp = tp; tp = cur;
            a0 += cur * cp[d];      a1 += cur * cp[9 + d];
            a2 += cur * cp[18 + d]; a3 += cur * cp[27 + d];
        }
    }
    float* op = out + (size_t)b * NOUT + o;
    op[0] = a0; op[1] = a1; op[2] = a2; op[3] = a3;
}

extern "C" void kernel_launch(void* const* d_in, const int* in_sizes, int n_in,
                              void* d_out, int out_size, void* d_ws, size_t ws_size,
                              hipStream_t stream) {
    const float* x  = (const float*)d_in[0];
    const float* cc = (const float*)d_in[1];
    float* out = (float*)d_out;

    const size_t wt_bytes = (size_t)KT2 * 1024 * sizeof(unsigned short);  // 16 MiB
    const size_t need = wt_bytes + 1024 * sizeof(float);
    if (ws_size >= need) {
        unsigned short* Wt = (unsigned short*)d_ws;
        float* bias = (float*)((char*)d_ws + wt_bytes);
        hipMemsetAsync(bias, 0, 1024 * sizeof(float), stream);
        prep_kernel<<<512, 256, 0, stream>>>(cc, Wt, bias);
        cheby_gemm<<<512, 256, 0, stream>>>(x, Wt, bias, out);
    } else {
        naive_kernel<<<8192, 256, 0, stream>>>(x, cc, out);
    }
}

// Round 4
// 274.272 us; speedup vs baseline: 1.1401x; 1.1401x over previous
//
#include <hip/hip_runtime.h>
#include <hip/hip_bf16.h>

#define AS1 __attribute__((address_space(1)))
#define AS3 __attribute__((address_space(3)))

typedef __attribute__((ext_vector_type(8))) short bf16x8;
typedef __attribute__((ext_vector_type(4))) float f32x4;

#define CSTRIDE 9216   // coeff row stride = O*(D+1)
#define KT2 8192       // GEMM K: polys T_1..T_8, k = (d-1)*1024 + i
#define NOUT 1024

__device__ __forceinline__ void gll16(const void* g, void* l) {
    __builtin_amdgcn_global_load_lds((const AS1 void*)g, (AS3 void*)l, 16, 0, 0);
}
static __device__ __forceinline__ unsigned short f2bf(float f) {
    union { __hip_bfloat16 h; unsigned short u; } cv;
    cv.h = __float2bfloat16(f);
    return cv.u;
}
static __device__ __forceinline__ float bf2f(unsigned short u) {
    union { float f; unsigned v; } c; c.v = (unsigned)u << 16; return c.f;
}
static __device__ __forceinline__ float fast_tanhf(float v) {
    float e = __expf(2.0f * v);
    return 1.0f - 2.0f / (e + 1.0f);
}

// ---------------------------------------------------------------------------
// Prep: cc (I=1024, O=1024, 9) f32 -> Wt[n][k] bf16, k=(d-1)*1024+i (d=1..8),
// PRE-SWIZZLED within each 64-chunk (Wt[n][e] = W[n][e ^ ((n&7)<<3)]) so a
// linear global_load_lds lands XOR-swizzled in LDS. Plus bias[o] = sum_i
// cc[i][o][0] (the T_0 term) via fp32 atomics.
// ---------------------------------------------------------------------------
__global__ void __launch_bounds__(256) prep_kernel(const float* __restrict__ cc,
                                                   unsigned short* __restrict__ Wt,
                                                   float* __restrict__ bias) {
    __shared__ unsigned short T[288 * 68];  // [f = nl*9 + d][il], pad 68
    const int t  = threadIdx.x;
    const int n0 = (blockIdx.x & 31) * 32;
    const int i0 = (blockIdx.x >> 5) * 64;

    for (int il = 0; il < 64; ++il) {
        const float* src = cc + (size_t)(i0 + il) * CSTRIDE + (size_t)n0 * 9;
        for (int f = t; f < 288; f += 256)
            T[f * 68 + il] = f2bf(src[f]);
    }
    __syncthreads();

    // 256 chunks (nl 0..31, dd 0..7 -> degree dd+1); 64 contiguous elems out.
#pragma unroll
    for (int it = 0; it < 16; ++it) {
        const int chunk = it * 16 + (t >> 4);
        const int nl = chunk >> 3;
        const int dd = chunk & 7;
        const int n  = n0 + nl;
        const int e0 = (t & 15) * 4;
        const int isrc = e0 ^ ((n & 7) << 3);   // consecutive 4 (swz bits >= 8)
        ushort4 v = *(const ushort4*)&T[(nl * 9 + dd + 1) * 68 + isrc];
        *(ushort4*)(Wt + (size_t)n * KT2 + dd * 1024 + i0 + e0) = v;
    }

    if (t < 32) {
        float s = 0.f;
#pragma unroll 8
        for (int il = 0; il < 64; ++il) s += bf2f(T[(t * 9) * 68 + il]);
        atomicAdd(&bias[n0 + t], s);
    }
}

// ---------------------------------------------------------------------------
// Fused GEMM: out[8192][1024] = Cheby_{1..8}(tanh(x)) @ Wt^T + bias
// 128x128 tile, 256 thr = 4 waves (64x64 each). A generated in-register
// (fp32 recurrence), single LDS buffer. B double-buffered, issued ONE STEP
// AHEAD via global_load_lds, left in flight across the barrier (counted
// vmcnt). R3 bug fixed: the ic==15 x-prefetch was dead code -> DCE'd ->
// vmcnt(12) undercounted -> stale B at the last step. Now: no x-prefetch at
// ic==15 and vmcnt(4) there instead.
// ---------------------------------------------------------------------------
__global__ void __launch_bounds__(256, 2)
cheby_gemm(const float* __restrict__ x, const unsigned short* __restrict__ Wt,
           const float* __restrict__ bias, float* __restrict__ out) {
    __shared__ unsigned short Asub[128 * 64];     // 16 KB, [row][kc] swizzled
    __shared__ unsigned short Bsub[2][128 * 64];  // 2 x 16 KB, [n][kc] swizzled

    const int id   = blockIdx.x;       // 512 blocks
    const int bcol = (id & 7) * 128;   // col strip fixed per XCD
    const int brow = (id >> 3) * 128;
    const int t    = threadIdx.x;
    const int lane = t & 63;
    const int w    = t >> 6;
    const int wr   = (w >> 1) * 64;
    const int wc   = (w & 1) * 64;
    const int l15  = lane & 15;
    const int lhi  = lane >> 4;

    const int gi0 = (t & 15) * 4;   // gen: i-quad
    const int gr  = t >> 4;         // gen: base row, covers gr+16p
    const int bn_loc = t >> 3;      // B staging row-in-chunk
    const int bpos   = (t & 7) * 8; // B staging elem offset (16 B)

    unsigned awoff[8];
#pragma unroll
    for (int p = 0; p < 8; ++p) {
        const int r = gr + 16 * p;
        awoff[p] = r * 128 + ((gi0 * 2) ^ ((r & 7) << 4));
    }

    f32x4 acc[4][4] = {};
    float x2[8][4], Tp[8][4], Tpp[8][4];
    float4 xt[8];

    // ---- prologue: x(ic=0) loads + B(step 0) into Bsub[0] ----
#pragma unroll
    for (int p = 0; p < 8; ++p)
        xt[p] = *(const float4*)(x + (size_t)(brow + gr + 16 * p) * 1024 + gi0);
#pragma unroll
    for (int c = 0; c < 4; ++c)
        gll16(Wt + (size_t)(bcol + c * 32 + bn_loc) * KT2 + bpos,
              (char*)Bsub[0] + c * 4096 + w * 1024);

#pragma unroll 1
    for (int ic = 0; ic < 16; ++ic) {
#pragma unroll
        for (int dd = 0; dd < 8; ++dd) {
            const int cur = dd & 1;          // (ic*8+dd)&1 == dd&1
            const int nxt = cur ^ 1;
            const int ddn = (dd + 1) & 7;
            const int icn = (dd == 7) ? ((ic + 1) & 15) : ic;
            const int kbn = ddn * 1024 + icn * 64;

            __builtin_amdgcn_s_barrier();   // bar1: MFMA(s-1) reads all done

            // next-ic x prefetch: NOT at ic==15 (would be dead -> DCE ->
            // vmcnt miscount -> race). Wave-uniform branch, once per 8 steps.
            const bool xpre = (dd == 7) && (ic != 15);
            if (xpre) {
#pragma unroll
                for (int p = 0; p < 8; ++p)
                    xt[p] = *(const float4*)(x + (size_t)(brow + gr + 16 * p) * 1024
                                             + icn * 64 + gi0);
            }

            // issue B(s+1) into the other buffer (in flight across barrier)
#pragma unroll
            for (int c = 0; c < 4; ++c)
                gll16(Wt + (size_t)(bcol + c * 32 + bn_loc) * KT2 + kbn + bpos,
                      (char*)Bsub[nxt] + c * 4096 + w * 1024);

            // generate A(s) = T_{dd+1} tile into Asub (single buffer)
            if (dd == 0) {
#pragma unroll
                for (int p = 0; p < 8; ++p) {
                    ushort4 pk; unsigned short* pks = (unsigned short*)&pk;
#pragma unroll
                    for (int j = 0; j < 4; ++j) {
                        x2[p][j] = 2.0f * fast_tanhf((&xt[p].x)[j]);
                        const float c = 0.5f * x2[p][j];
                        Tp[p][j] = c; Tpp[p][j] = 1.0f;
                        pks[j] = f2bf(c);
                    }
                    *(ushort4*)((char*)Asub + awoff[p]) = pk;
                }
            } else {
#pragma unroll
                for (int p = 0; p < 8; ++p) {
                    ushort4 pk; unsigned short* pks = (unsigned short*)&pk;
#pragma unroll
                    for (int j = 0; j < 4; ++j) {
                        const float c = __builtin_fmaf(x2[p][j], Tp[p][j], -Tpp[p][j]);
                        Tpp[p][j] = Tp[p][j]; Tp[p][j] = c;
                        pks[j] = f2bf(c);
                    }
                    *(ushort4*)((char*)Asub + awoff[p]) = pk;
                }
            }

            // counted wait: drain exactly B(s).
            // outstanding: B(s)=4 (always oldest) + B(s+1)=4 + (x=8 if xpre).
            if (xpre) {
                asm volatile("s_waitcnt vmcnt(12) lgkmcnt(0)" ::: "memory");
            } else {
                asm volatile("s_waitcnt vmcnt(4) lgkmcnt(0)" ::: "memory");
            }
            __builtin_amdgcn_s_barrier();   // bar2: A written, B(s) landed

            // MFMA phase: BK=64 -> 2 k-steps of 32
#pragma unroll
            for (int ks = 0; ks < 2; ++ks) {
                bf16x8 af[4], bfr[4];
#pragma unroll
                for (int mf = 0; mf < 4; ++mf) {
                    const int row = wr + mf * 16 + l15;
                    af[mf] = *(const bf16x8*)((const char*)Asub + row * 128 +
                              ((ks * 64 + lhi * 16) ^ ((row & 7) << 4)));
                }
#pragma unroll
                for (int nf = 0; nf < 4; ++nf) {
                    const int n = wc + nf * 16 + l15;
                    bfr[nf] = *(const bf16x8*)((const char*)Bsub[cur] + n * 128 +
                              ((ks * 64 + lhi * 16) ^ ((n & 7) << 4)));
                }
#pragma unroll
                for (int mf = 0; mf < 4; ++mf)
#pragma unroll
                    for (int nf = 0; nf < 4; ++nf)
                        acc[mf][nf] = __builtin_amdgcn_mfma_f32_16x16x32_bf16(
                            af[mf], bfr[nf], acc[mf][nf], 0, 0, 0);
            }
        }
    }

    // epilogue: C/D layout col = lane&15, row = (lane>>4)*4 + reg; + bias
    float bv[4];
#pragma unroll
    for (int nf = 0; nf < 4; ++nf) bv[nf] = bias[bcol + wc + nf * 16 + l15];
#pragma unroll
    for (int mf = 0; mf < 4; ++mf)
#pragma unroll
        for (int nf = 0; nf < 4; ++nf)
#pragma unroll
            for (int ri = 0; ri < 4; ++ri) {
                const int orow = brow + wr + mf * 16 + lhi * 4 + ri;
                const int ocol = bcol + wc + nf * 16 + l15;
                out[(size_t)orow * NOUT + ocol] = acc[mf][nf][ri] + bv[nf];
            }
}

// ---------------------------------------------------------------------------
// Fallback (only if ws too small): correct but slow fp32 path.
// ---------------------------------------------------------------------------
__global__ void __launch_bounds__(256) naive_kernel(const float* __restrict__ x,
                                                    const float* __restrict__ cc,
                                                    float* __restrict__ out) {
    __shared__ float xs[1024];
    const int b = blockIdx.x;
    const int t = threadIdx.x;
#pragma unroll
    for (int j = 0; j < 4; ++j)
        xs[t * 4 + j] = fast_tanhf(x[(size_t)b * 1024 + t * 4 + j]);
    __syncthreads();

    const int o = t * 4;
    float a0 = 0.f, a1 = 0.f, a2 = 0.f, a3 = 0.f;
    for (int i = 0; i < 1024; ++i) {
        const float* cp = cc + (size_t)i * CSTRIDE + (size_t)o * 9;
        const float xv = xs[i];
        float tpp = 1.0f, tp = xv;
        a0 += cp[0];  a1 += cp[9];  a2 += cp[18];  a3 += cp[27];
        a0 += xv * cp[1]; a1 += xv * cp[10]; a2 += xv * cp[19]; a3 += xv * cp[28];
#pragma unroll
        for (int d = 2; d <= 8; ++d) {
            const float cur = 2.0f * xv * tp - tpp;
            tpp = tp; tp = cur;
            a0 += cur * cp[d];      a1 += cur * cp[9 + d];
            a2 += cur * cp[18 + d]; a3 += cur * cp[27 + d];
        }
    }
    float* op = out + (size_t)b * NOUT + o;
    op[0] = a0; op[1] = a1; op[2] = a2; op[3] = a3;
}

extern "C" void kernel_launch(void* const* d_in, const int* in_sizes, int n_in,
                              void* d_out, int out_size, void* d_ws, size_t ws_size,
                              hipStream_t stream) {
    const float* x  = (const float*)d_in[0];
    const float* cc = (const float*)d_in[1];
    float* out = (float*)d_out;

    const size_t wt_bytes = (size_t)KT2 * 1024 * sizeof(unsigned short);  // 16 MiB
    const size_t need = wt_bytes + 1024 * sizeof(float);
    if (ws_size >= need) {
        unsigned short* Wt = (unsigned short*)d_ws;
        float* bias = (float*)((char*)d_ws + wt_bytes);
        hipMemsetAsync(bias, 0, 1024 * sizeof(float), stream);
        prep_kernel<<<512, 256, 0, stream>>>(cc, Wt, bias);
        cheby_gemm<<<512, 256, 0, stream>>>(x, Wt, bias, out);
    } else {
        naive_kernel<<<8192, 256, 0, stream>>>(x, cc, out);
    }
}

// Round 5
// 251.080 us; speedup vs baseline: 1.2454x; 1.0924x over previous
//
#include <hip/hip_runtime.h>
#include <hip/hip_bf16.h>

#define AS1 __attribute__((address_space(1)))
#define AS3 __attribute__((address_space(3)))

typedef __attribute__((ext_vector_type(8))) short bf16x8;
typedef __attribute__((ext_vector_type(4))) float f32x4;

#define CSTRIDE 9216   // coeff row stride = O*(D+1)
#define KT2 8192       // GEMM K: polys T_1..T_8, k = (d-1)*1024 + i
#define NOUT 1024

__device__ __forceinline__ void gll16(const void* g, void* l) {
    __builtin_amdgcn_global_load_lds((const AS1 void*)g, (AS3 void*)l, 16, 0, 0);
}
static __device__ __forceinline__ unsigned short f2bf(float f) {
    union { __hip_bfloat16 h; unsigned short u; } cv;
    cv.h = __float2bfloat16(f);
    return cv.u;
}
static __device__ __forceinline__ float bf2f(unsigned short u) {
    union { float f; unsigned v; } c; c.v = (unsigned)u << 16; return c.f;
}
static __device__ __forceinline__ float fast_tanhf(float v) {
    float e = __expf(2.0f * v);
    return 1.0f - 2.0f / (e + 1.0f);
}

// ---------------------------------------------------------------------------
// Prep: cc (I=1024, O=1024, 9) f32 -> Wt[n][k] bf16, k=(d-1)*1024+i (d=1..8),
// PRE-SWIZZLED within each 64-chunk (Wt[n][e] = W[n][e ^ ((n&7)<<3)]) so a
// linear global_load_lds lands XOR-swizzled in LDS. Plus bias[o] = sum_i
// cc[i][o][0] (the T_0 term) via fp32 atomics.  (unchanged from R4 — proven)
// ---------------------------------------------------------------------------
__global__ void __launch_bounds__(256) prep_kernel(const float* __restrict__ cc,
                                                   unsigned short* __restrict__ Wt,
                                                   float* __restrict__ bias) {
    __shared__ unsigned short T[288 * 68];  // [f = nl*9 + d][il], pad 68
    const int t  = threadIdx.x;
    const int n0 = (blockIdx.x & 31) * 32;
    const int i0 = (blockIdx.x >> 5) * 64;

    for (int il = 0; il < 64; ++il) {
        const float* src = cc + (size_t)(i0 + il) * CSTRIDE + (size_t)n0 * 9;
        for (int f = t; f < 288; f += 256)
            T[f * 68 + il] = f2bf(src[f]);
    }
    __syncthreads();

#pragma unroll
    for (int it = 0; it < 16; ++it) {
        const int chunk = it * 16 + (t >> 4);
        const int nl = chunk >> 3;
        const int dd = chunk & 7;
        const int n  = n0 + nl;
        const int e0 = (t & 15) * 4;
        const int isrc = e0 ^ ((n & 7) << 3);
        ushort4 v = *(const ushort4*)&T[(nl * 9 + dd + 1) * 68 + isrc];
        *(ushort4*)(Wt + (size_t)n * KT2 + dd * 1024 + i0 + e0) = v;
    }

    if (t < 32) {
        float s = 0.f;
#pragma unroll 8
        for (int il = 0; il < 64; ++il) s += bf2f(T[(t * 9) * 68 + il]);
        atomicAdd(&bias[n0 + t], s);
    }
}

// ---------------------------------------------------------------------------
// Fused GEMM: out[8192][1024] = Cheby_{1..8}(tanh(x)) @ Wt^T + bias
// R1's proven 2-barrier schedule (full __syncthreads drains, single A and B
// LDS buffers), with: K=8192 (T_0 -> bias) and BM=64 tile -> grid 1024 ->
// 4 blocks/CU (__launch_bounds__(256,4), 24 KB LDS/block) so cross-block
// wave overlap hides the per-block barrier drains (m114 mechanism).
// 4 waves, each 32x64 output. NO source-level pipelining (R2/R4 lesson).
// ---------------------------------------------------------------------------
__global__ void __launch_bounds__(256, 4)
cheby_gemm(const float* __restrict__ x, const unsigned short* __restrict__ Wt,
           const float* __restrict__ bias, float* __restrict__ out) {
    __shared__ unsigned short Asub[64 * 64];    // 8 KB, [row][kc] swizzled
    __shared__ unsigned short Bsub[128 * 64];   // 16 KB, [n][kc] swizzled

    const int id   = blockIdx.x;       // 1024 blocks
    const int bcol = (id & 7) * 128;   // col strip fixed per XCD
    const int brow = (id >> 3) * 64;
    const int t    = threadIdx.x;
    const int lane = t & 63;
    const int w    = t >> 6;
    const int wr   = (w >> 1) * 32;    // wave row offset (2x2 wave grid)
    const int wc   = (w & 1) * 64;     // wave col offset
    const int l15  = lane & 15;
    const int lhi  = lane >> 4;

    const int gi0 = (t & 15) * 4;   // gen: i-quad
    const int gr  = t >> 4;         // gen: base row 0..15, covers gr+16p, p<4
    const int bn_loc = t >> 3;      // B staging row-in-chunk 0..31
    const int bpos   = (t & 7) * 8; // B staging elem offset (16 B)

    unsigned awoff[4];
#pragma unroll
    for (int p = 0; p < 4; ++p) {
        const int r = gr + 16 * p;
        awoff[p] = r * 128 + ((gi0 * 2) ^ ((r & 7) << 4));
    }

    f32x4 acc[2][4] = {};
    float x2[4][4], Tp[4][4], Tpp[4][4];

#pragma unroll 1
    for (int ic = 0; ic < 16; ++ic) {
        // load this ic's x sub-tile (compiler schedules the waits)
        float4 xt[4];
#pragma unroll
        for (int p = 0; p < 4; ++p)
            xt[p] = *(const float4*)(x + (size_t)(brow + gr + 16 * p) * 1024
                                     + ic * 64 + gi0);

#pragma unroll
        for (int dd = 0; dd < 8; ++dd) {
            __syncthreads();   // MFMA(s-1) reads done before overwriting LDS

            // stage B(s): 4 chunks x (64 lanes x 16 B), linear dest per wave
            const int kb = dd * 1024 + ic * 64;
#pragma unroll
            for (int c = 0; c < 4; ++c)
                gll16(Wt + (size_t)(bcol + c * 32 + bn_loc) * KT2 + kb + bpos,
                      (char*)Bsub + c * 4096 + w * 1024);

            // generate A(s) = T_{dd+1} tile (fp32 recurrence, bf16 pack)
            if (dd == 0) {
#pragma unroll
                for (int p = 0; p < 4; ++p) {
                    ushort4 pk; unsigned short* pks = (unsigned short*)&pk;
#pragma unroll
                    for (int j = 0; j < 4; ++j) {
                        x2[p][j] = 2.0f * fast_tanhf((&xt[p].x)[j]);
                        const float c = 0.5f * x2[p][j];
                        Tp[p][j] = c; Tpp[p][j] = 1.0f;
                        pks[j] = f2bf(c);
                    }
                    *(ushort4*)((char*)Asub + awoff[p]) = pk;
                }
            } else {
#pragma unroll
                for (int p = 0; p < 4; ++p) {
                    ushort4 pk; unsigned short* pks = (unsigned short*)&pk;
#pragma unroll
                    for (int j = 0; j < 4; ++j) {
                        const float c = __builtin_fmaf(x2[p][j], Tp[p][j], -Tpp[p][j]);
                        Tpp[p][j] = Tp[p][j]; Tp[p][j] = c;
                        pks[j] = f2bf(c);
                    }
                    *(ushort4*)((char*)Asub + awoff[p]) = pk;
                }
            }

            __syncthreads();   // full drain: A written, B landed

            // MFMA phase: BK=64 -> 2 k-steps of 32; wave tile 32x64
#pragma unroll
            for (int ks = 0; ks < 2; ++ks) {
                bf16x8 af[2], bfr[4];
#pragma unroll
                for (int mf = 0; mf < 2; ++mf) {
                    const int row = wr + mf * 16 + l15;
                    af[mf] = *(const bf16x8*)((const char*)Asub + row * 128 +
                              ((ks * 64 + lhi * 16) ^ ((row & 7) << 4)));
                }
#pragma unroll
                for (int nf = 0; nf < 4; ++nf) {
                    const int n = wc + nf * 16 + l15;
                    bfr[nf] = *(const bf16x8*)((const char*)Bsub + n * 128 +
                              ((ks * 64 + lhi * 16) ^ ((n & 7) << 4)));
                }
#pragma unroll
                for (int mf = 0; mf < 2; ++mf)
#pragma unroll
                    for (int nf = 0; nf < 4; ++nf)
                        acc[mf][nf] = __builtin_amdgcn_mfma_f32_16x16x32_bf16(
                            af[mf], bfr[nf], acc[mf][nf], 0, 0, 0);
            }
        }
    }

    // epilogue: C/D layout col = lane&15, row = (lane>>4)*4 + reg; + bias
    float bv[4];
#pragma unroll
    for (int nf = 0; nf < 4; ++nf) bv[nf] = bias[bcol + wc + nf * 16 + l15];
#pragma unroll
    for (int mf = 0; mf < 2; ++mf)
#pragma unroll
        for (int nf = 0; nf < 4; ++nf)
#pragma unroll
            for (int ri = 0; ri < 4; ++ri) {
                const int orow = brow + wr + mf * 16 + lhi * 4 + ri;
                const int ocol = bcol + wc + nf * 16 + l15;
                out[(size_t)orow * NOUT + ocol] = acc[mf][nf][ri] + bv[nf];
            }
}

// ---------------------------------------------------------------------------
// Fallback (only if ws too small): correct but slow fp32 path.
// ---------------------------------------------------------------------------
__global__ void __launch_bounds__(256) naive_kernel(const float* __restrict__ x,
                                                    const float* __restrict__ cc,
                                                    float* __restrict__ out) {
    __shared__ float xs[1024];
    const int b = blockIdx.x;
    const int t = threadIdx.x;
#pragma unroll
    for (int j = 0; j < 4; ++j)
        xs[t * 4 + j] = fast_tanhf(x[(size_t)b * 1024 + t * 4 + j]);
    __syncthreads();

    const int o = t * 4;
    float a0 = 0.f, a1 = 0.f, a2 = 0.f, a3 = 0.f;
    for (int i = 0; i < 1024; ++i) {
        const float* cp = cc + (size_t)i * CSTRIDE + (size_t)o * 9;
        const float xv = xs[i];
        float tpp = 1.0f, tp = xv;
        a0 += cp[0];  a1 += cp[9];  a2 += cp[18];  a3 += cp[27];
        a0 += xv * cp[1]; a1 += xv * cp[10]; a2 += xv * cp[19]; a3 += xv * cp[28];
#pragma unroll
        for (int d = 2; d <= 8; ++d) {
            const float cur = 2.0f * xv * tp - tpp;
            tpp = tp; tp = cur;
            a0 += cur * cp[d];      a1 += cur * cp[9 + d];
            a2 += cur * cp[18 + d]; a3 += cur * cp[27 + d];
        }
    }
    float* op = out + (size_t)b * NOUT + o;
    op[0] = a0; op[1] = a1; op[2] = a2; op[3] = a3;
}

extern "C" void kernel_launch(void* const* d_in, const int* in_sizes, int n_in,
                              void* d_out, int out_size, void* d_ws, size_t ws_size,
                              hipStream_t stream) {
    const float* x  = (const float*)d_in[0];
    const float* cc = (const float*)d_in[1];
    float* out = (float*)d_out;

    const size_t wt_bytes = (size_t)KT2 * 1024 * sizeof(unsigned short);  // 16 MiB
    const size_t need = wt_bytes + 1024 * sizeof(float);
    if (ws_size >= need) {
        unsigned short* Wt = (unsigned short*)d_ws;
        float* bias = (float*)((char*)d_ws + wt_bytes);
        hipMemsetAsync(bias, 0, 1024 * sizeof(float), stream);
        prep_kernel<<<512, 256, 0, stream>>>(cc, Wt, bias);
        cheby_gemm<<<1024, 256, 0, stream>>>(x, Wt, bias, out);
    } else {
        naive_kernel<<<8192, 256, 0, stream>>>(x, cc, out);
    }
}